// Round 11
// baseline (1021.755 us; speedup 1.0000x reference)
//
#include <hip/hip_runtime.h>
#include <hip/hip_bf16.h>

typedef _Float16 f16x8 __attribute__((ext_vector_type(8)));
typedef float f32x4 __attribute__((ext_vector_type(4)));

static constexpr int BB = 8;
static constexpr int TT = 2048;
static constexpr int DD = 1024;
static constexpr int MM = BB * TT;      // 16384
static constexpr int NN = 7 * DD;      // 7168
static constexpr int APS = 2048;       // A' layout: [x1 | x2]
static constexpr int NCSUB = 32;
static constexpr int LC = TT / NCSUB;  // 64
static constexpr int BD = BB * DD;     // 8192
#define EPS_ 1e-6f

// ---- ws layout ----
// cmpA (67MB) | zsP (33.5MB) | hpnP (33.5MB) | Bp (44MB slot) | SM (6MB) | Ap (chunked)
static constexpr size_t SZ_CMPA = (size_t)MM * DD * 4;
static constexpr size_t SZ_PLN  = (size_t)MM * DD * 2;
static constexpr size_t SZ_BP   = (size_t)NN * 3072 * 2;
static constexpr size_t SZ_SM   = (size_t)NCSUB * BD * 4;
static constexpr size_t OFF_ZS  = SZ_CMPA;
static constexpr size_t OFF_HPN = OFF_ZS + SZ_PLN;
static constexpr size_t OFF_BP  = OFF_HPN + SZ_PLN;
static constexpr size_t OFF_SM  = OFF_BP + SZ_BP;
static constexpr size_t OFF_AP  = OFF_SM + 6 * SZ_SM;       // 184,549,376
static constexpr size_t CHUNK_BYTES = (size_t)MM * APS * 2; // 64MB at NCH=1

// ---- helpers ----
__device__ __forceinline__ unsigned short bf_rne(float f) {
    unsigned u = __builtin_bit_cast(unsigned, f);
    unsigned r = (u + 0x7fffu + ((u >> 16) & 1u)) >> 16;
    return (unsigned short)r;
}
__device__ __forceinline__ float bf2f(unsigned short u) {
    return __builtin_bit_cast(float, ((unsigned)u) << 16);
}
__device__ __forceinline__ float f16f(unsigned short u) {
    return (float)__builtin_bit_cast(_Float16, u);
}
__device__ __forceinline__ unsigned short f16b(float f) {
    return __builtin_bit_cast(unsigned short, (_Float16)f);
}
__device__ __forceinline__ float sigm(float x) { return 1.0f / (1.0f + __expf(-x)); }

typedef __attribute__((address_space(3))) void lds_void;
typedef const __attribute__((address_space(1))) void gbl_void;
__device__ __forceinline__ void gload16(const void* g, void* l) {
    __builtin_amdgcn_global_load_lds((gbl_void*)g, (lds_void*)l, 16, 0, 0);
}

// ---- prep: scaled f16 hi/lo splits, interleaved B rows ----
// Bp1 (K=1024): rows 0..2047 = {r,z} at d*2+g; rows 2048..3071 = hp at 2048+d. Single term w1.
// Bp2 (K=3072): rows d*4+{0:k,1:v,2:de,3:al}, [w1|w1|w2].
__global__ __launch_bounds__(256) void prep_w(const float* __restrict__ W,
                                              _Float16* __restrict__ Bp1,
                                              _Float16* __restrict__ Bp2) {
    int i = blockIdx.x * 256 + threadIdx.x;          // NN*1024
    int o = i >> 10, k = i & 1023;
    int g = o >> 10, d = o & 1023;
    float wv = W[i] * 512.0f;
    _Float16 w1 = (_Float16)wv;
    _Float16 w2 = (_Float16)(wv - (float)w1);
    if (g == 0 || g == 1) {
        Bp1[(size_t)(d * 2 + g) * 1024 + k] = w1;
    } else if (g == 4) {
        Bp1[(size_t)(2048 + d) * 1024 + k] = w1;
    } else {
        int g2 = (g < 4 ? g - 2 : g - 3);            // k->0, v->1, de->2, al->3
        size_t base = (size_t)(d * 4 + g2) * 3072 + k;
        Bp2[base] = w1; Bp2[base + 1024] = w1; Bp2[base + 2048] = w2;
    }
}

__global__ __launch_bounds__(256) void prep_x(const float* __restrict__ x,
                                              _Float16* __restrict__ Ap,
                                              int tc, int Tc, int tcShift) {
    int i = blockIdx.x * 256 + threadIdx.x;          // Mc*1024
    int rho = i >> 10, k = i & 1023;
    int b = rho >> tcShift, tau = rho & (Tc - 1);
    size_t m = (size_t)b * TT + (size_t)tc * Tc + tau;
    float xv = x[m * DD + k] * 16.0f;
    _Float16 x1 = (_Float16)xv;
    _Float16 x2 = (_Float16)(xv - (float)x1);
    size_t base = (size_t)rho * APS + k;
    Ap[base] = x1; Ap[base + 1024] = x2;
}

// ---- GEMM (verified r6/r9 2-phase structure + T2 XOR-swizzle), 256x128 tile, 8 waves ----
// KIND==1: {r,z}/hp interleaved -> writes zsP/hpnP. KIND==2: {k,v,de,al} -> writes cmpA.
template<int KT, int NTILES, int KIND>
__global__ __launch_bounds__(512) void gemm_k(const _Float16* __restrict__ Ap,
                                              const _Float16* __restrict__ Bp,
                                              const float* __restrict__ bias,
                                              ushort2* __restrict__ cmpA,
                                              unsigned short* __restrict__ zsP,
                                              unsigned short* __restrict__ hpnP,
                                              int Mt, int tcOff, int Tc, int tcShift) {
    constexpr int KSTR = KT * 64;
    __shared__ __align__(16) _Float16 As[256 * 64];
    __shared__ __align__(16) _Float16 Bs[128 * 64];
    int nwg = Mt * NTILES;
    int bid = blockIdx.x;
    int cpx = nwg >> 3;
    int swz = (bid & 7) * cpx + (bid >> 3);          // nwg % 8 == 0 always here
    int bm = swz / NTILES, bn = swz % NTILES;
    int m0 = bm * 256, n0 = bn * 128;
    int tid = threadIdx.x;
    int w = tid >> 6, l = tid & 63;
    int wm = w >> 1, wn = w & 1;
    int lrow = l & 15, kg = l >> 4;
    f32x4 acc[4][4] = {};
    const char* Ab = (const char*)Ap;
    const char* Bb = (const char*)Bp;
    for (int k0 = 0; k0 < KT * 64; k0 += 64) {
        int ak0 = k0 & 2047;                         // fold third K-block onto x1
#pragma unroll
        for (int q = 0; q < 4; ++q) {
            int c = q * 512 + tid;
            int row = c >> 3, sgg = (c & 7) ^ (row & 7);
            gload16(Ab + ((size_t)(m0 + row) * APS + ak0 + sgg * 8) * 2, (char*)As + c * 16);
        }
#pragma unroll
        for (int q = 0; q < 2; ++q) {
            int c = q * 512 + tid;
            int row = c >> 3, sgg = (c & 7) ^ (row & 7);
            gload16(Bb + ((size_t)(n0 + row) * KSTR + k0 + sgg * 8) * 2, (char*)Bs + c * 16);
        }
        __syncthreads();
#pragma unroll
        for (int kk = 0; kk < 64; kk += 32) {
            f16x8 af[4], bfr[4];
            int sgb = kg + (kk >> 3);
#pragma unroll
            for (int i = 0; i < 4; ++i) {
                int r = wm * 64 + i * 16 + lrow;
                af[i] = *(const f16x8*)(As + r * 64 + (size_t)((sgb ^ (r & 7)) * 8));
            }
#pragma unroll
            for (int j = 0; j < 4; ++j) {
                int r = wn * 64 + j * 16 + lrow;
                bfr[j] = *(const f16x8*)(Bs + r * 64 + (size_t)((sgb ^ (r & 7)) * 8));
            }
#pragma unroll
            for (int i = 0; i < 4; ++i)
#pragma unroll
                for (int j = 0; j < 4; ++j)
                    acc[i][j] = __builtin_amdgcn_mfma_f32_16x16x32_f16(af[i], bfr[j], acc[i][j], 0, 0, 0);
        }
        __syncthreads();
    }
    // ---- fused epilogue ----
    const float inv = 1.0f / 8192.0f;
#pragma unroll
    for (int j = 0; j < 4; ++j) {
        int o = n0 + wn * 64 + j * 16 + lrow;
#pragma unroll
        for (int i = 0; i < 4; ++i) {
            int rbase = m0 + wm * 64 + i * 16 + kg * 4;
#pragma unroll
            for (int r = 0; r < 4; ++r) {
                int rb = rbase + r;
                int bb = rb >> tcShift, tau = rb & (Tc - 1);
                size_t gm = (size_t)bb * TT + tcOff + tau;
                if (KIND == 1) {
                    if (n0 < 2048) {                 // {r,z} region (block-uniform)
                        int d = o >> 1, g = o & 1;   // g == l&1
                        float val = acc[i][j][r] * inv + bias[g * 1024 + d];
                        float part = __shfl_xor(val, 1);
                        if (g == 1) {                // z-lane: part = r
                            float zs = sigm(val * rsqrtf((part * part + val * val) * 0.5f + EPS_));
                            zsP[gm * DD + d] = f16b(zs);
                        }
                    } else {                         // hp region
                        int d = o - 2048;
                        float val = acc[i][j][r] * inv + bias[4 * 1024 + d];
                        hpnP[gm * DD + d] = f16b(val * rsqrtf(val * val + EPS_));
                    }
                } else {
                    int g2 = o & 3, d = o >> 2;      // g2 == l&3
                    int og = (g2 == 0 ? 2 : g2 == 1 ? 3 : g2 == 2 ? 5 : 6);
                    float val = acc[i][j][r] * inv + bias[og * 1024 + d];
                    if (g2 >= 2) val = sigm(val * rsqrtf(val * val + EPS_));  // ds, as
                    float v1 = __shfl_xor(val, 1);
                    float v2 = __shfl_xor(val, 2);
                    float v3 = __shfl_xor(val, 3);
                    if ((l & 3) == 0) {              // k-lane: v1=v, v2=ds, v3=as
                        float rk2 = (val * val + v1 * v1) * 0.5f + EPS_;
                        float kv = (val * v1) / (rk2 * (rk2 + EPS_));
                        float akv = v3 * kv;
                        ushort2 ua; ua.x = bf_rne(akv); ua.y = f16b(v2);
                        cmpA[gm * DD + d] = ua;
                    }
                }
            }
        }
    }
}

// ---- recurrence passes ----
__global__ __launch_bounds__(256) void passA(const ushort2* __restrict__ cmpA,
                                             float* __restrict__ SP, float* __restrict__ SQ) {
    int bid = blockIdx.x;                            // 1024 = 8*32*4
    int b = bid >> 7, rem = bid & 127;
    int ch = rem >> 2, d = (rem & 3) * 256 + threadIdx.x;
    const ushort2* p = cmpA + ((size_t)(b * TT + ch * LC)) * DD + d;
    float P = 1.0f, Q = 0.0f;
#pragma unroll 4
    for (int i = 0; i < LC; ++i) {
        ushort2 u = p[(size_t)i * DD];
        float akv = bf2f(u.x), ds = f16f(u.y);
        P *= ds; Q = ds * Q + akv;
    }
    int bd = b * DD + d;
    SP[ch * BD + bd] = P; SQ[ch * BD + bd] = Q;
}

__global__ __launch_bounds__(256) void passB(const float* __restrict__ s0,
                                             const float* __restrict__ SP, const float* __restrict__ SQ,
                                             float* __restrict__ Sst, float* __restrict__ sT) {
    int bd = blockIdx.x * 256 + threadIdx.x;
    float s = s0[bd];
    for (int ch = 0; ch < NCSUB; ++ch) {
        Sst[ch * BD + bd] = s;
        s = SP[ch * BD + bd] * s + SQ[ch * BD + bd];
    }
    sT[bd] = s;
}

__global__ __launch_bounds__(256) void passC(const ushort2* __restrict__ cmpA,
                                             const unsigned short* __restrict__ zsP,
                                             const unsigned short* __restrict__ hpnP,
                                             const float* __restrict__ Sst,
                                             float* __restrict__ HZ, float* __restrict__ HR) {
    int bid = blockIdx.x;
    int b = bid >> 7, rem = bid & 127;
    int ch = rem >> 2, d = (rem & 3) * 256 + threadIdx.x;
    int bd = b * DD + d;
    float s = Sst[ch * BD + bd];
    float Z = 1.0f, R = 0.0f;
    size_t base = ((size_t)(b * TT + ch * LC)) * DD + d;
#pragma unroll 4
    for (int i = 0; i < LC; ++i) {
        ushort2 ua = cmpA[base + (size_t)i * DD];
        float akv = bf2f(ua.x), ds = f16f(ua.y);
        float zs = f16f(zsP[base + (size_t)i * DD]);
        float hpn = f16f(hpnP[base + (size_t)i * DD]);
        s = ds * s + akv;
        float c = 2.0f * sigm(2.0f * (hpn + s)) - 1.0f;
        Z *= zs; R = zs * R + (1.0f - zs) * c;
    }
    HZ[ch * BD + bd] = Z; HR[ch * BD + bd] = R;
}

__global__ __launch_bounds__(256) void passD(const float* __restrict__ h0,
                                             const float* __restrict__ HZ, const float* __restrict__ HR,
                                             float* __restrict__ Hst) {
    int bd = blockIdx.x * 256 + threadIdx.x;
    float h = h0[bd];
    for (int ch = 0; ch < NCSUB; ++ch) {
        Hst[ch * BD + bd] = h;
        h = HZ[ch * BD + bd] * h + HR[ch * BD + bd];
    }
}

__global__ __launch_bounds__(256) void passE(const ushort2* __restrict__ cmpA,
                                             const unsigned short* __restrict__ zsP,
                                             const unsigned short* __restrict__ hpnP,
                                             const float* __restrict__ Sst,
                                             const float* __restrict__ Hst,
                                             float* __restrict__ out) {
    int bid = blockIdx.x;
    int b = bid >> 7, rem = bid & 127;
    int ch = rem >> 2, d = (rem & 3) * 256 + threadIdx.x;
    int bd = b * DD + d;
    float s = Sst[ch * BD + bd];
    float h = Hst[ch * BD + bd];
    size_t base = ((size_t)(b * TT + ch * LC)) * DD + d;
    float* op = out + base;
#pragma unroll 4
    for (int i = 0; i < LC; ++i) {
        ushort2 ua = cmpA[base + (size_t)i * DD];
        float akv = bf2f(ua.x), ds = f16f(ua.y);
        float zs = f16f(zsP[base + (size_t)i * DD]);
        float hpn = f16f(hpnP[base + (size_t)i * DD]);
        s = ds * s + akv;
        float c = 2.0f * sigm(2.0f * (hpn + s)) - 1.0f;
        h = (1.0f - zs) * c + zs * h;
        op[(size_t)i * DD] = h;
    }
}

__global__ __launch_bounds__(256) void sentinel_k(float* __restrict__ sT) {
    int i = blockIdx.x * 256 + threadIdx.x;
    if (i < BD) sT[i] = 1e9f;
}

extern "C" void kernel_launch(void* const* d_in, const int* in_sizes, int n_in,
                              void* d_out, int out_size, void* d_ws, size_t ws_size,
                              hipStream_t stream) {
    const float* x    = (const float*)d_in[0];
    const float* h0   = (const float*)d_in[1];
    const float* s0   = (const float*)d_in[2];
    const float* W    = (const float*)d_in[3];
    const float* bias = (const float*)d_in[4];
    float* out = (float*)d_out;
    float* sT  = out + (size_t)MM * DD;
    char* ws = (char*)d_ws;

    int NCH = 0;
    for (int c : {1, 2, 4, 8, 16, 32}) {
        if (OFF_AP + CHUNK_BYTES / c <= ws_size) { NCH = c; break; }
    }
    if (!NCH) {
        sentinel_k<<<BD / 256, 256, 0, stream>>>(sT);
        return;
    }
    int Mc = MM / NCH;
    int Tc = TT / NCH;
    int tcShift = 31 - __builtin_clz(Tc);
    int Mt = Mc / 256;

    ushort2* cmpA        = (ushort2*)ws;
    unsigned short* zsP  = (unsigned short*)(ws + OFF_ZS);
    unsigned short* hpnP = (unsigned short*)(ws + OFF_HPN);
    _Float16* Bp1 = (_Float16*)(ws + OFF_BP);                           // 3072x1024 f16
    _Float16* Bp2 = (_Float16*)(ws + OFF_BP + (size_t)3072 * 1024 * 2); // 4096x3072 f16
    float* SP  = (float*)(ws + OFF_SM);
    float* SQ  = (float*)(ws + OFF_SM + 1 * SZ_SM);
    float* Sst = (float*)(ws + OFF_SM + 2 * SZ_SM);
    float* HZ  = (float*)(ws + OFF_SM + 3 * SZ_SM);
    float* HR  = (float*)(ws + OFF_SM + 4 * SZ_SM);
    float* Hst = (float*)(ws + OFF_SM + 5 * SZ_SM);
    _Float16* Ap = (_Float16*)(ws + OFF_AP);

    prep_w<<<(NN * DD) / 256, 256, 0, stream>>>(W, Bp1, Bp2);
    for (int tc = 0; tc < NCH; ++tc) {
        int tcOff = tc * Tc;
        prep_x<<<Mc * 4, 256, 0, stream>>>(x, Ap, tc, Tc, tcShift);
        gemm_k<16, 24, 1><<<Mt * 24, 512, 0, stream>>>(Ap, Bp1, bias, cmpA, zsP, hpnP, Mt, tcOff, Tc, tcShift);
        gemm_k<48, 32, 2><<<Mt * 32, 512, 0, stream>>>(Ap, Bp2, bias, cmpA, zsP, hpnP, Mt, tcOff, Tc, tcShift);
    }
    passA<<<BB * NCSUB * 4, 256, 0, stream>>>(cmpA, SP, SQ);
    passB<<<BD / 256, 256, 0, stream>>>(s0, SP, SQ, Sst, sT);
    passC<<<BB * NCSUB * 4, 256, 0, stream>>>(cmpA, zsP, hpnP, Sst, HZ, HR);
    passD<<<BD / 256, 256, 0, stream>>>(h0, HZ, HR, Hst);
    passE<<<BB * NCSUB * 4, 256, 0, stream>>>(cmpA, zsP, hpnP, Sst, Hst, out);
}

// Round 12
// 753.210 us; speedup vs baseline: 1.3565x; 1.3565x over previous
//
#include <hip/hip_runtime.h>
#include <hip/hip_bf16.h>

typedef _Float16 f16x8 __attribute__((ext_vector_type(8)));
typedef float f32x4 __attribute__((ext_vector_type(4)));

static constexpr int BB = 8;
static constexpr int TT = 2048;
static constexpr int DD = 1024;
static constexpr int MM = BB * TT;      // 16384
static constexpr int NN = 7 * DD;      // 7168
static constexpr int APS = 2048;       // A' layout: [x1 | x2], stride 2048
static constexpr int NCSUB = 32;       // recurrence sub-chunks over T
static constexpr int LC = TT / NCSUB;  // 64
static constexpr int BD = BB * DD;     // 8192
#define EPS_ 1e-6f

// ---- ws layout (adaptive tail) ----
static constexpr size_t SZ_CMP = (size_t)MM * DD * 8;       // cmpA 67MB + cmpB 67MB
static constexpr size_t SZ_BP  = (size_t)NN * 3072 * 2;     // 44MB slot (31.5MB used)
static constexpr size_t SZ_SM  = (size_t)NCSUB * BD * 4;    // 1MB
static constexpr size_t OFF_BP  = SZ_CMP;
static constexpr size_t OFF_SM  = OFF_BP + SZ_BP;
static constexpr size_t OFF_AP  = OFF_SM + 6 * SZ_SM;       // 184,549,376
static constexpr size_t CHUNK_BYTES = (size_t)MM * 18432;   // Ap(4096)+Gc1(6144)+Gc2(8192) per row

// ---- helpers ----
__device__ __forceinline__ unsigned short bf_rne(float f) {
    unsigned u = __builtin_bit_cast(unsigned, f);
    unsigned r = (u + 0x7fffu + ((u >> 16) & 1u)) >> 16;
    return (unsigned short)r;
}
__device__ __forceinline__ float bf2f(unsigned short u) {
    return __builtin_bit_cast(float, ((unsigned)u) << 16);
}
__device__ __forceinline__ float f16f(unsigned short u) {
    return (float)__builtin_bit_cast(_Float16, u);
}
__device__ __forceinline__ unsigned short f16b(float f) {
    return __builtin_bit_cast(unsigned short, (_Float16)f);
}
__device__ __forceinline__ float sigm(float x) { return 1.0f / (1.0f + __expf(-x)); }

typedef __attribute__((address_space(3))) void lds_void;
typedef const __attribute__((address_space(1))) void gbl_void;
__device__ __forceinline__ void gload16(const void* g, void* l) {
    __builtin_amdgcn_global_load_lds((gbl_void*)g, (lds_void*)l, 16, 0, 0);
}

// ---- prep: scaled f16 hi/lo splits, two B buffers ----
// Bp1: gates {r,z,hp} -> rows {0,1,2} x K=1024, single term w1
// Bp2: gates {k,v,de,al} -> rows {0,1,2,3} x K=3072, [w1|w1|w2]
__global__ __launch_bounds__(256) void prep_w(const float* __restrict__ W,
                                              _Float16* __restrict__ Bp1,
                                              _Float16* __restrict__ Bp2) {
    int i = blockIdx.x * 256 + threadIdx.x;          // NN*1024
    int o = i >> 10, k = i & 1023;
    int g = o >> 10, d = o & 1023;
    float wv = W[i] * 512.0f;
    _Float16 w1 = (_Float16)wv;
    _Float16 w2 = (_Float16)(wv - (float)w1);
    if (g == 0 || g == 1 || g == 4) {
        int r1 = (g == 4 ? 2 : g) * 1024 + d;
        Bp1[(size_t)r1 * 1024 + k] = w1;
    } else {
        int r2 = (g < 4 ? g - 2 : g - 3) * 1024 + d; // 2->0, 3->1, 5->2, 6->3
        size_t base = (size_t)r2 * 3072 + k;
        Bp2[base] = w1; Bp2[base + 1024] = w1; Bp2[base + 2048] = w2;
    }
}

__global__ __launch_bounds__(256) void prep_x(const float* __restrict__ x,
                                              _Float16* __restrict__ Ap,
                                              int tc, int Tc, int tcShift) {
    int i = blockIdx.x * 256 + threadIdx.x;          // Mc*1024
    int rho = i >> 10, k = i & 1023;
    int b = rho >> tcShift, tau = rho & (Tc - 1);
    size_t m = (size_t)b * TT + (size_t)tc * Tc + tau;
    float xv = x[m * DD + k] * 16.0f;
    _Float16 x1 = (_Float16)xv;
    _Float16 x2 = (_Float16)(xv - (float)x1);
    size_t base = (size_t)rho * APS + k;
    Ap[base] = x1; Ap[base + 1024] = x2;
}

// ---- GEMM (verified r6 structure + T2 XOR-swizzle), tile 256x128, 8 waves ----
// A' k-index: logical k0 in [0,KT*64); physical column = k0 & 2047 ([x1|x2|x1] folded).
// LDS: As 256x64 f16 (32 KB), Bs 128x64 (16 KB). 128 B rows = 8 segs of 16 B.
// Linear gload_lds dest; global source seg = lin ^ (row&7); ds_read seg = want ^ (row&7).
template<int KT, int NTILES, int NCOLS, int KIND>
__global__ __launch_bounds__(512) void gemm_k(const _Float16* __restrict__ Ap,
                                              const _Float16* __restrict__ Bp,
                                              const float* __restrict__ bias,
                                              _Float16* __restrict__ Gc, int Mt) {
    constexpr int KSTR = KT * 64;                    // B row stride
    __shared__ __align__(16) _Float16 As[256 * 64];
    __shared__ __align__(16) _Float16 Bs[128 * 64];
    int nwg = Mt * NTILES;
    int bid = blockIdx.x;
    int cpx = nwg >> 3;
    int swz = (bid & 7) * cpx + (bid >> 3);          // nwg % 8 == 0 for all NCH here
    int bm = swz / NTILES, bn = swz % NTILES;
    int m0 = bm * 256, n0 = bn * 128;
    int tid = threadIdx.x;
    int w = tid >> 6, l = tid & 63;
    int wm = w >> 1, wn = w & 1;                     // 4x2 wave grid, per-wave 64x64
    int lrow = l & 15, kg = l >> 4;
    f32x4 acc[4][4] = {};
    const char* Ab = (const char*)Ap;
    const char* Bb = (const char*)Bp;
    for (int k0 = 0; k0 < KT * 64; k0 += 64) {
        int ak0 = k0 & 2047;                         // fold third block onto x1
#pragma unroll
        for (int q = 0; q < 4; ++q) {                // stage A: 256 rows x 64 cols
            int c = q * 512 + tid;
            int row = c >> 3, sgg = (c & 7) ^ (row & 7);
            gload16(Ab + ((size_t)(m0 + row) * APS + ak0 + sgg * 8) * 2, (char*)As + c * 16);
        }
#pragma unroll
        for (int q = 0; q < 2; ++q) {                // stage B: 128 rows x 64 cols
            int c = q * 512 + tid;
            int row = c >> 3, sgg = (c & 7) ^ (row & 7);
            gload16(Bb + ((size_t)(n0 + row) * KSTR + k0 + sgg * 8) * 2, (char*)Bs + c * 16);
        }
        __syncthreads();                             // drains vmcnt before use
#pragma unroll
        for (int kk = 0; kk < 64; kk += 32) {
            f16x8 af[4], bfr[4];
            int sgb = kg + (kk >> 3);                // wanted source seg 0..7
#pragma unroll
            for (int i = 0; i < 4; ++i) {
                int r = wm * 64 + i * 16 + lrow;
                af[i] = *(const f16x8*)(As + r * 64 + (size_t)((sgb ^ (r & 7)) * 8));
            }
#pragma unroll
            for (int j = 0; j < 4; ++j) {
                int r = wn * 64 + j * 16 + lrow;
                bfr[j] = *(const f16x8*)(Bs + r * 64 + (size_t)((sgb ^ (r & 7)) * 8));
            }
#pragma unroll
            for (int i = 0; i < 4; ++i)
#pragma unroll
                for (int j = 0; j < 4; ++j)
                    acc[i][j] = __builtin_amdgcn_mfma_f32_16x16x32_f16(af[i], bfr[j], acc[i][j], 0, 0, 0);
        }
        __syncthreads();                             // protect LDS before next stage
    }
    const float inv = 1.0f / 8192.0f;
#pragma unroll
    for (int j = 0; j < 4; ++j) {
        int o = n0 + wn * 64 + j * 16 + lrow;
        int g = o >> 10, d = o & 1023;
        float bv;
        if (KIND == 1) bv = bias[(g == 2 ? 4 : g) * 1024 + d];        // {r,z,hp}
        else           bv = bias[(g < 2 ? g + 2 : g + 3) * 1024 + d]; // {k,v,de,al}
#pragma unroll
        for (int i = 0; i < 4; ++i) {
            int rb = m0 + wm * 64 + i * 16 + kg * 4;
#pragma unroll
            for (int r = 0; r < 4; ++r) {
                float val = acc[i][j][r] * inv + bv;
                if (KIND == 1) {
                    if (g == 2) val = val * rsqrtf(val * val + EPS_);         // hpn
                } else {
                    if (g >= 2) val = sigm(val * rsqrtf(val * val + EPS_));  // ds, as
                }
                Gc[(size_t)(rb + r) * NCOLS + o] = (_Float16)val;
            }
        }
    }
}

// ---- compact: gates -> cmpA{akv bf16, ds f16}, cmpB{zs f16, hpn f16} ----
__global__ __launch_bounds__(256) void compact_k(const _Float16* __restrict__ Gc1,
                                                 const _Float16* __restrict__ Gc2,
                                                 ushort2* __restrict__ cmpA,
                                                 ushort2* __restrict__ cmpB,
                                                 int tc, int Tc, int tcShift) {
    int idx = blockIdx.x * 256 + threadIdx.x;        // Mc*1024
    int rho = idx >> 10, d = idx & 1023;
    const _Float16* row1 = Gc1 + (size_t)rho * 3072;
    const _Float16* row2 = Gc2 + (size_t)rho * 4096;
    float r   = row1[d], z  = row1[1024 + d], hpn = row1[2048 + d];
    float k   = row2[d], v  = row2[1024 + d];
    float ds  = row2[2048 + d], as = row2[3072 + d];
    float rc2 = (r * r + z * z) * 0.5f + EPS_;
    float zs = sigm(z * rsqrtf(rc2));
    float rk2 = (k * k + v * v) * 0.5f + EPS_;
    float kv = (k * v) / (rk2 * (rk2 + EPS_));
    float akv = as * kv;
    int b = rho >> tcShift, tau = rho & (Tc - 1);
    size_t m = (size_t)b * TT + (size_t)tc * Tc + tau;
    ushort2 ua; ua.x = bf_rne(akv); ua.y = f16b(ds);
    ushort2 ub; ub.x = f16b(zs);    ub.y = f16b(hpn);
    cmpA[m * DD + d] = ua;
    cmpB[m * DD + d] = ub;
}

// ---- recurrence passes ----
__global__ __launch_bounds__(256) void passA(const ushort2* __restrict__ cmpA,
                                             float* __restrict__ SP, float* __restrict__ SQ) {
    int bid = blockIdx.x;                            // 1024 = 8*32*4
    int b = bid >> 7, rem = bid & 127;
    int ch = rem >> 2, d = (rem & 3) * 256 + threadIdx.x;
    const ushort2* p = cmpA + ((size_t)(b * TT + ch * LC)) * DD + d;
    float P = 1.0f, Q = 0.0f;
#pragma unroll 4
    for (int i = 0; i < LC; ++i) {
        ushort2 u = p[(size_t)i * DD];
        float akv = bf2f(u.x), ds = f16f(u.y);
        P *= ds; Q = ds * Q + akv;
    }
    int bd = b * DD + d;
    SP[ch * BD + bd] = P; SQ[ch * BD + bd] = Q;
}

__global__ __launch_bounds__(256) void passB(const float* __restrict__ s0,
                                             const float* __restrict__ SP, const float* __restrict__ SQ,
                                             float* __restrict__ Sst, float* __restrict__ sT) {
    int bd = blockIdx.x * 256 + threadIdx.x;
    float s = s0[bd];
    for (int ch = 0; ch < NCSUB; ++ch) {
        Sst[ch * BD + bd] = s;
        s = SP[ch * BD + bd] * s + SQ[ch * BD + bd];
    }
    sT[bd] = s;
}

__global__ __launch_bounds__(256) void passC(const ushort2* __restrict__ cmpA,
                                             const ushort2* __restrict__ cmpB,
                                             const float* __restrict__ Sst,
                                             float* __restrict__ HZ, float* __restrict__ HR) {
    int bid = blockIdx.x;
    int b = bid >> 7, rem = bid & 127;
    int ch = rem >> 2, d = (rem & 3) * 256 + threadIdx.x;
    int bd = b * DD + d;
    float s = Sst[ch * BD + bd];
    float Z = 1.0f, R = 0.0f;
    size_t base = ((size_t)(b * TT + ch * LC)) * DD + d;
#pragma unroll 4
    for (int i = 0; i < LC; ++i) {
        ushort2 ua = cmpA[base + (size_t)i * DD];
        ushort2 ub = cmpB[base + (size_t)i * DD];
        float akv = bf2f(ua.x), ds = f16f(ua.y), zs = f16f(ub.x), hpn = f16f(ub.y);
        s = ds * s + akv;
        float c = 2.0f * sigm(2.0f * (hpn + s)) - 1.0f;
        Z *= zs; R = zs * R + (1.0f - zs) * c;
    }
    HZ[ch * BD + bd] = Z; HR[ch * BD + bd] = R;
}

__global__ __launch_bounds__(256) void passD(const float* __restrict__ h0,
                                             const float* __restrict__ HZ, const float* __restrict__ HR,
                                             float* __restrict__ Hst) {
    int bd = blockIdx.x * 256 + threadIdx.x;
    float h = h0[bd];
    for (int ch = 0; ch < NCSUB; ++ch) {
        Hst[ch * BD + bd] = h;
        h = HZ[ch * BD + bd] * h + HR[ch * BD + bd];
    }
}

__global__ __launch_bounds__(256) void passE(const ushort2* __restrict__ cmpA,
                                             const ushort2* __restrict__ cmpB,
                                             const float* __restrict__ Sst,
                                             const float* __restrict__ Hst,
                                             float* __restrict__ out) {
    int bid = blockIdx.x;
    int b = bid >> 7, rem = bid & 127;
    int ch = rem >> 2, d = (rem & 3) * 256 + threadIdx.x;
    int bd = b * DD + d;
    float s = Sst[ch * BD + bd];
    float h = Hst[ch * BD + bd];
    size_t base = ((size_t)(b * TT + ch * LC)) * DD + d;
    float* op = out + base;
#pragma unroll 4
    for (int i = 0; i < LC; ++i) {
        ushort2 ua = cmpA[base + (size_t)i * DD];
        ushort2 ub = cmpB[base + (size_t)i * DD];
        float akv = bf2f(ua.x), ds = f16f(ua.y), zs = f16f(ub.x), hpn = f16f(ub.y);
        s = ds * s + akv;
        float c = 2.0f * sigm(2.0f * (hpn + s)) - 1.0f;
        h = (1.0f - zs) * c + zs * h;
        op[(size_t)i * DD] = h;
    }
}

__global__ __launch_bounds__(256) void sentinel_k(float* __restrict__ sT) {
    int i = blockIdx.x * 256 + threadIdx.x;
    if (i < BD) sT[i] = 1e9f;
}

extern "C" void kernel_launch(void* const* d_in, const int* in_sizes, int n_in,
                              void* d_out, int out_size, void* d_ws, size_t ws_size,
                              hipStream_t stream) {
    const float* x    = (const float*)d_in[0];
    const float* h0   = (const float*)d_in[1];
    const float* s0   = (const float*)d_in[2];
    const float* W    = (const float*)d_in[3];
    const float* bias = (const float*)d_in[4];
    float* out = (float*)d_out;
    float* sT  = out + (size_t)MM * DD;
    char* ws = (char*)d_ws;

    int NCH = 0;
    for (int c : {2, 4, 8, 16, 32}) {
        if (OFF_AP + CHUNK_BYTES / c <= ws_size) { NCH = c; break; }
    }
    if (!NCH) {
        sentinel_k<<<BD / 256, 256, 0, stream>>>(sT);
        return;
    }
    int Mc = MM / NCH;
    int Tc = TT / NCH;
    int tcShift = 31 - __builtin_clz(Tc);
    int Mt = Mc / 256;

    ushort2* cmpA = (ushort2*)ws;
    ushort2* cmpB = (ushort2*)(ws + (size_t)MM * DD * 4);
    _Float16* Bp1 = (_Float16*)(ws + OFF_BP);                           // 3072x1024 f16
    _Float16* Bp2 = (_Float16*)(ws + OFF_BP + (size_t)3072 * 1024 * 2); // 4096x3072 f16
    float* SP  = (float*)(ws + OFF_SM);
    float* SQ  = (float*)(ws + OFF_SM + 1 * SZ_SM);
    float* Sst = (float*)(ws + OFF_SM + 2 * SZ_SM);
    float* HZ  = (float*)(ws + OFF_SM + 3 * SZ_SM);
    float* HR  = (float*)(ws + OFF_SM + 4 * SZ_SM);
    float* Hst = (float*)(ws + OFF_SM + 5 * SZ_SM);
    _Float16* Ap  = (_Float16*)(ws + OFF_AP);
    _Float16* Gc1 = (_Float16*)(ws + OFF_AP + (size_t)Mc * APS * 2);
    _Float16* Gc2 = Gc1 + (size_t)Mc * 3072;

    prep_w<<<(NN * DD) / 256, 256, 0, stream>>>(W, Bp1, Bp2);
    for (int tc = 0; tc < NCH; ++tc) {
        prep_x<<<Mc * 4, 256, 0, stream>>>(x, Ap, tc, Tc, tcShift);
        gemm_k<16, 24, 3072, 1><<<Mt * 24, 512, 0, stream>>>(Ap, Bp1, bias, Gc1, Mt);
        gemm_k<48, 32, 4096, 2><<<Mt * 32, 512, 0, stream>>>(Ap, Bp2, bias, Gc2, Mt);
        compact_k<<<Mc * 4, 256, 0, stream>>>(Gc1, Gc2, cmpA, cmpB, tc, Tc, tcShift);
    }
    passA<<<BB * NCSUB * 4, 256, 0, stream>>>(cmpA, SP, SQ);
    passB<<<BD / 256, 256, 0, stream>>>(s0, SP, SQ, Sst, sT);
    passC<<<BB * NCSUB * 4, 256, 0, stream>>>(cmpA, cmpB, Sst, HZ, HR);
    passD<<<BD / 256, 256, 0, stream>>>(h0, HZ, HR, Hst);
    passE<<<BB * NCSUB * 4, 256, 0, stream>>>(cmpA, cmpB, Sst, Hst, out);
}